// Round 1
// baseline (273.038 us; speedup 1.0000x reference)
//
#include <hip/hip_runtime.h>
#include <stdint.h>

// Problem constants
#define B_  16
#define C_  256
#define H_  64
#define W_  64
#define P_  4096      // H*W
#define E_  8
#define HP_ 66        // padded spatial (64 + 2)

typedef __bf16 bf16x8 __attribute__((ext_vector_type(8)));
typedef float  f32x4  __attribute__((ext_vector_type(4)));

// ---------- helpers ----------
__device__ __forceinline__ unsigned short f2bf(float f) {
    union { float f; unsigned int u; } v; v.f = f;
    unsigned int u = v.u;
    unsigned int r = (u + 0x7fffu + ((u >> 16) & 1u)) >> 16;  // RNE
    return (unsigned short)r;
}

__device__ __forceinline__ void async_load16(const void* g, void* l) {
    __builtin_amdgcn_global_load_lds(
        (const __attribute__((address_space(1))) void*)g,
        (__attribute__((address_space(3))) void*)l, 16, 0, 0);
}

// ---------- k_xpose: Xp[b][h+1][w+1][c] = bf16(x[b][c][h][w]) + fused channel-sum ----------
__global__ void k_xpose(const float* __restrict__ x, unsigned short* __restrict__ Xp,
                        float* __restrict__ xsum) {
    const int bid = blockIdx.x;       // 16 * 64 * 4
    const int b  = bid >> 8;
    const int h  = (bid >> 2) & 63;
    const int cg = bid & 3;
    const int c0 = cg << 6;
    const int tid = threadIdx.x;
    __shared__ float tile[64][65];
    {
        const int ci = tid >> 2, wseg = tid & 3;
        const float* src = x + ((size_t)(b * 256 + c0 + ci) << 12) + (h << 6) + wseg * 16;
        float s = 0.f;
#pragma unroll
        for (int i = 0; i < 4; ++i) {
            float4 v = *(const float4*)(src + i * 4);
            tile[ci][wseg * 16 + i * 4 + 0] = v.x;
            tile[ci][wseg * 16 + i * 4 + 1] = v.y;
            tile[ci][wseg * 16 + i * 4 + 2] = v.z;
            tile[ci][wseg * 16 + i * 4 + 3] = v.w;
            s += v.x + v.y + v.z + v.w;
        }
        // reduce the 4 wseg lanes (consecutive) and add to channel sum
        s += __shfl_down(s, 1, 64);
        s += __shfl_down(s, 2, 64);
        if ((tid & 3) == 0) atomicAdd(&xsum[b * 256 + c0 + ci], s);
    }
    __syncthreads();
    {
        const int w = tid >> 2, cs = tid & 3;
        unsigned short ov[16] __attribute__((aligned(16)));
#pragma unroll
        for (int k = 0; k < 16; ++k) ov[k] = f2bf(tile[cs * 16 + k][w]);
        unsigned short* dst = Xp + ((size_t)((b * HP_ + h + 1) * HP_ + (w + 1)) << 8) + c0 + cs * 16;
        ((uint4*)dst)[0] = ((const uint4*)ov)[0];
        ((uint4*)dst)[1] = ((const uint4*)ov)[1];
    }
}

// ---------- k_mix: mix[b][e] = softmax_e(dense(conv_w @ xmean + cb) + db) ----------
__global__ void k_mix(const float* __restrict__ xsum,
                      const float* __restrict__ cw, const float* __restrict__ cb,
                      const float* __restrict__ dw, const float* __restrict__ db,
                      float* __restrict__ mix) {
    const int b = blockIdx.x, tid = threadIdx.x;
    __shared__ float sxm[256];
    __shared__ float spool[256];
    __shared__ float sl[8];
    sxm[tid] = xsum[b * 256 + tid] * (1.0f / P_);
    __syncthreads();
    float a = cb[tid];
    for (int c = 0; c < 256; ++c) a += cw[tid * 256 + c] * sxm[c];
    spool[tid] = a;
    __syncthreads();
    if (tid < 8) {
        float l = db[tid];
        for (int d = 0; d < 256; ++d) l += dw[tid * 256 + d] * spool[d];
        sl[tid] = l;
    }
    __syncthreads();
    if (tid < 8) {
        float m = sl[0];
        for (int e = 1; e < 8; ++e) m = fmaxf(m, sl[e]);
        float den = 0.f;
        for (int e = 0; e < 8; ++e) den += __expf(sl[e] - m);
        mix[b * 8 + tid] = __expf(sl[tid] - m) / den;
    }
}

// ---------- k_mixkern: Wg[b][o][t][ic] = bf16( sum_e mix[b][e] * KE[e][o][ic][t] ) ----------
// Coalesced rewrite: block = (o, ic-half); stage 8 x 1152 contiguous floats in LDS.
__global__ void k_mixkern(const float* __restrict__ KE, const float* __restrict__ mix,
                          unsigned short* __restrict__ Wg) {
    const int o    = blockIdx.x >> 1;
    const int half = blockIdx.x & 1;
    const int ic0  = half << 7;
    const int tid  = threadIdx.x;
    __shared__ float s[8][1152];     // 36.9 KB
    __shared__ float smix[128];
    if (tid < 128) smix[tid] = mix[tid];
#pragma unroll
    for (int e = 0; e < 8; ++e) {
        const float* src = KE + (size_t)(e * 256 + o) * 2304 + ic0 * 9;
#pragma unroll
        for (int k = 0; k < 4; ++k) s[e][k * 256 + tid] = src[k * 256 + tid];
        if (tid < 128) s[e][1024 + tid] = src[1024 + tid];
    }
    __syncthreads();
    const int icl = tid & 127;
    const int b0  = (tid >> 7) << 3;     // 0 or 8
#pragma unroll
    for (int t = 0; t < 9; ++t) {
        float v[8];
#pragma unroll
        for (int e = 0; e < 8; ++e) v[e] = s[e][icl * 9 + t];
#pragma unroll
        for (int bb = 0; bb < 8; ++bb) {
            const int b = b0 + bb;
            float acc = 0.f;
#pragma unroll
            for (int e = 0; e < 8; ++e) acc += smix[b * 8 + e] * v[e];
            Wg[((size_t)(b * 256 + o) * 9 + t) * 256 + ic0 + icl] = f2bf(acc);
        }
    }
}

// ---------- k_border: zero the pad border of Xp ----------
__global__ void k_border(unsigned short* __restrict__ Xp) {
    const int gid = blockIdx.x * 256 + threadIdx.x;   // 0..133119
    const int pix = gid >> 5;                          // 0..4159 (16*260)
    const int chunk = gid & 31;
    const int b = pix / 260;
    const int j = pix - b * 260;
    int h, w;
    if (j < 66)       { h = 0;  w = j; }
    else if (j < 132) { h = 65; w = j - 66; }
    else { int jj = j - 132; h = 1 + (jj & 63); w = (jj < 64) ? 0 : 65; }
    const uint4 z = {0u, 0u, 0u, 0u};
    *(uint4*)(Xp + ((size_t)((b * HP_ + h) * HP_ + w) << 8) + chunk * 8) = z;
}

// ---------- k_gemm: implicit-im2col bf16 MFMA GEMM, 2-phase double-buffered ----------
// Per block: sample b, 128 output channels, 128 pixels (2 rows x 64).
// K = 9 taps * 256 ch = 2304, BK = 64 -> 36 K-steps. A = Wg[b][o][k], B^T = Xp pixel rows.
// XCD-pinned: b is derived from bid&7 so each sample's 64 blocks share one L2.
// LDS chunk-slot XOR swizzle (slot = chunk ^ (row&7)) applied on the *global
// source* side of global_load_lds, so fragment ds_read_b128 is conflict-free.
// T3-minimum schedule: prefetch step s+1 into the spare LDS buffer BEFORE
// computing step s; ONE __syncthreads() per K-step (its implicit vmcnt(0)
// drains the prefetch after the MFMA block has already run). 64 KB LDS ->
// 2 blocks/CU; intra-block overlap replaces the lost inter-block overlap.
__global__ __launch_bounds__(256) void k_gemm(const unsigned short* __restrict__ Wg,
                                              const unsigned short* __restrict__ Xp,
                                              float* __restrict__ out) {
    __shared__ __align__(16) unsigned short lA[2][128 * 64];   // 2 x 16 KB
    __shared__ __align__(16) unsigned short lB[2][128 * 64];   // 2 x 16 KB
    const int tid = threadIdx.x;
    const int bid = blockIdx.x;
    const int xcd = bid & 7;
    const int g   = bid >> 3;
    const int b   = xcd + ((g >> 6) << 3);   // all 64 blocks of sample b on one XCD
    const int rem = g & 63;
    const int ot  = rem & 1;
    const int rp  = rem >> 1;
    const int o0  = ot << 7;
    const int h0  = rp << 1;

    const int wid  = tid >> 6;
    const int lane = tid & 63;
    const int wm   = wid >> 1;
    const int wn   = wid & 1;
    const int ql   = lane & 15;
    const int quad = lane >> 4;
    const int sw   = ql & 7;      // read-side swizzle key (= row&7 of fragment row)

    const int srow = tid >> 3;    // 0..31
    const int sseg = tid & 7;     // 0..7  (LDS slot this thread fills)
    const int csrc = sseg ^ (srow & 7);   // global chunk that belongs in this slot

    f32x4 acc[4][4];
#pragma unroll
    for (int i = 0; i < 4; ++i)
#pragma unroll
        for (int j = 0; j < 4; ++j) acc[i][j] = (f32x4)0.0f;

    // A element index: ((b*256 + o0 + srow + 32j)*9 + t)*256 + kc*64 + csrc*8
    const size_t abase = (size_t)(b * 256 + o0 + srow) * 9 * 256 + csrc * 8;

    // Issue the 8 global_load_lds for K-step S into buffer BUF.
    // S in [0,36): t = S>>2 (tap), kc = S&3 (64-ch group within tap).
#define STAGE(BUF, S) do {                                                       \
        const int s_  = (S);                                                     \
        const int t_  = s_ >> 2;                                                 \
        const int kc_ = s_ & 3;                                                  \
        const int kh_ = t_ / 3;                                                  \
        const int kw_ = t_ - kh_ * 3;                                            \
        char* la_ = (char*)lA[BUF];                                              \
        char* lb_ = (char*)lB[BUF];                                              \
        _Pragma("unroll")                                                        \
        for (int j = 0; j < 4; ++j) {                                            \
            const unsigned short* ga = Wg + abase + (size_t)j * 32 * 9 * 256     \
                                       + (size_t)t_ * 256 + kc_ * 64;            \
            async_load16(ga, la_ + tid * 16 + j * 4096);                         \
        }                                                                        \
        _Pragma("unroll")                                                        \
        for (int j = 0; j < 4; ++j) {                                            \
            const int pix = srow + 32 * j;                                       \
            const int pr  = pix >> 6;                                            \
            const int w_  = pix & 63;                                            \
            const unsigned short* gb = Xp                                        \
                + ((size_t)((b * HP_ + h0 + pr + kh_) * HP_ + (w_ + kw_)) << 8)  \
                + kc_ * 64 + csrc * 8;                                           \
            async_load16(gb, lb_ + tid * 16 + j * 4096);                         \
        }                                                                        \
    } while (0)

    // 2x (8 ds_read_b128 + 16 MFMA) from buffer BUF.
#define COMPUTE(BUF) do {                                                        \
        char* la_ = (char*)lA[BUF];                                              \
        char* lb_ = (char*)lB[BUF];                                              \
        _Pragma("unroll")                                                        \
        for (int kk = 0; kk < 2; ++kk) {                                         \
            bf16x8 af[4], bv[4];                                                 \
            _Pragma("unroll")                                                    \
            for (int mi = 0; mi < 4; ++mi)                                       \
                af[mi] = *(const bf16x8*)(la_ + (wm * 64 + mi * 16 + ql) * 128   \
                                          + ((((kk << 2) | quad) ^ sw) << 4));   \
            _Pragma("unroll")                                                    \
            for (int ni = 0; ni < 4; ++ni)                                       \
                bv[ni] = *(const bf16x8*)(lb_ + (wn * 64 + ni * 16 + ql) * 128   \
                                          + ((((kk << 2) | quad) ^ sw) << 4));   \
            _Pragma("unroll")                                                    \
            for (int mi = 0; mi < 4; ++mi)                                       \
                _Pragma("unroll")                                                \
                for (int ni = 0; ni < 4; ++ni)                                   \
                    acc[mi][ni] = __builtin_amdgcn_mfma_f32_16x16x32_bf16(       \
                        af[mi], bv[ni], acc[mi][ni], 0, 0, 0);                   \
        }                                                                        \
    } while (0)

    STAGE(0, 0);
    __syncthreads();                 // drain prologue loads (vmcnt(0) implicit)
    for (int s = 0; s < 36; s += 2) {
        STAGE(1, s + 1);             // prefetch next step into spare buffer
        COMPUTE(0);                  // MFMA on current buffer hides load latency
        __syncthreads();             // implicit vmcnt(0): buf1 ready, buf0 free
        if (s + 2 < 36) STAGE(0, s + 2);
        COMPUTE(1);
        __syncthreads();
    }
#undef STAGE
#undef COMPUTE

    // Epilogue: C/D layout col=lane&15 (pixel), row=quad*4+reg (o)
    const int h = h0 + wn;
#pragma unroll
    for (int mi = 0; mi < 4; ++mi) {
        const int o = o0 + wm * 64 + mi * 16 + quad * 4;
#pragma unroll
        for (int ni = 0; ni < 4; ++ni) {
            const int w = ni * 16 + ql;
            float* po = out + ((size_t)(b * 256 + o) << 12) + (h << 6) + w;
#pragma unroll
            for (int r = 0; r < 4; ++r) po[(size_t)r << 12] = acc[mi][ni][r];
        }
    }
}

// ---------- launch ----------
extern "C" void kernel_launch(void* const* d_in, const int* in_sizes, int n_in,
                              void* d_out, int out_size, void* d_ws, size_t ws_size,
                              hipStream_t stream) {
    const float* x  = (const float*)d_in[0];
    const float* KE = (const float*)d_in[1];
    const float* cw = (const float*)d_in[2];
    const float* cb = (const float*)d_in[3];
    const float* dw = (const float*)d_in[4];
    const float* db = (const float*)d_in[5];
    float* out = (float*)d_out;

    char* ws = (char*)d_ws;
    float* xsum           = (float*)(ws + 0);            // 16*256*4    = 16 KB
    float* mix            = (float*)(ws + 16384);        // 16*8*4      = 512 B
    unsigned short* Wg    = (unsigned short*)(ws + 32768);            // 18.87 MB
    unsigned short* Xp    = (unsigned short*)(ws + 32768 + 18874368); // 35.68 MB

    hipMemsetAsync(xsum, 0, B_ * C_ * sizeof(float), stream);
    k_xpose  <<<dim3(B_ * H_ * 4),    dim3(256), 0, stream>>>(x, Xp, xsum);
    k_border <<<dim3(520),            dim3(256), 0, stream>>>(Xp);
    k_mix    <<<dim3(B_),             dim3(256), 0, stream>>>(xsum, cw, cb, dw, db, mix);
    k_mixkern<<<dim3(C_ * 2),         dim3(256), 0, stream>>>(KE, mix, Wg);
    k_gemm   <<<dim3(B_ * 2 * 32),    dim3(256), 0, stream>>>(Wg, Xp, out);
}

// Round 3
// 259.038 us; speedup vs baseline: 1.0540x; 1.0540x over previous
//
#include <hip/hip_runtime.h>
#include <stdint.h>

// Problem constants
#define B_  16
#define C_  256
#define H_  64
#define W_  64
#define P_  4096      // H*W
#define E_  8
#define HP_ 66        // padded spatial (64 + 2)

typedef __bf16 bf16x8 __attribute__((ext_vector_type(8)));
typedef float  f32x4  __attribute__((ext_vector_type(4)));

// ---------- helpers ----------
__device__ __forceinline__ unsigned short f2bf(float f) {
    union { float f; unsigned int u; } v; v.f = f;
    unsigned int u = v.u;
    unsigned int r = (u + 0x7fffu + ((u >> 16) & 1u)) >> 16;  // RNE
    return (unsigned short)r;
}

__device__ __forceinline__ void async_load16(const void* g, void* l) {
    __builtin_amdgcn_global_load_lds(
        (const __attribute__((address_space(1))) void*)g,
        (__attribute__((address_space(3))) void*)l, 16, 0, 0);
}

// ---------- k_xpose: Xp[b][h+1][w+1][c] = bf16(x[b][c][h][w]) + fused channel-sum
//            + fused pad-border zeroing (blocks 0..519 also zero a border slice) ----------
__global__ void k_xpose(const float* __restrict__ x, unsigned short* __restrict__ Xp,
                        float* __restrict__ xsum) {
    const int bid = blockIdx.x;       // 16 * 64 * 4
    const int tid = threadIdx.x;

    // Fused border zeroing (was k_border): disjoint from interior writes below.
    if (bid < 520) {
        const int gid = bid * 256 + tid;               // 0..133119
        const int pix = gid >> 5;                      // 0..4159 (16*260)
        const int chunk = gid & 31;
        const int bb = pix / 260;
        const int j = pix - bb * 260;
        int h, w;
        if (j < 66)       { h = 0;  w = j; }
        else if (j < 132) { h = 65; w = j - 66; }
        else { int jj = j - 132; h = 1 + (jj & 63); w = (jj < 64) ? 0 : 65; }
        const uint4 z = {0u, 0u, 0u, 0u};
        *(uint4*)(Xp + ((size_t)((bb * HP_ + h) * HP_ + w) << 8) + chunk * 8) = z;
    }

    const int b  = bid >> 8;
    const int h  = (bid >> 2) & 63;
    const int cg = bid & 3;
    const int c0 = cg << 6;
    __shared__ float tile[64][65];
    {
        const int ci = tid >> 2, wseg = tid & 3;
        const float* src = x + ((size_t)(b * 256 + c0 + ci) << 12) + (h << 6) + wseg * 16;
        float s = 0.f;
#pragma unroll
        for (int i = 0; i < 4; ++i) {
            float4 v = *(const float4*)(src + i * 4);
            tile[ci][wseg * 16 + i * 4 + 0] = v.x;
            tile[ci][wseg * 16 + i * 4 + 1] = v.y;
            tile[ci][wseg * 16 + i * 4 + 2] = v.z;
            tile[ci][wseg * 16 + i * 4 + 3] = v.w;
            s += v.x + v.y + v.z + v.w;
        }
        // reduce the 4 wseg lanes (consecutive) and add to channel sum
        s += __shfl_down(s, 1, 64);
        s += __shfl_down(s, 2, 64);
        if ((tid & 3) == 0) atomicAdd(&xsum[b * 256 + c0 + ci], s);
    }
    __syncthreads();
    {
        const int w = tid >> 2, cs = tid & 3;
        unsigned short ov[16] __attribute__((aligned(16)));
#pragma unroll
        for (int k = 0; k < 16; ++k) ov[k] = f2bf(tile[cs * 16 + k][w]);
        unsigned short* dst = Xp + ((size_t)((b * HP_ + h + 1) * HP_ + (w + 1)) << 8) + c0 + cs * 16;
        ((uint4*)dst)[0] = ((const uint4*)ov)[0];
        ((uint4*)dst)[1] = ((const uint4*)ov)[1];
    }
}

// ---------- k_mix: mix[b][e] = softmax_e(dense(conv_w @ xmean + cb) + db) ----------
// float4 matvec + wave-parallel logit reduction (was 8 serial lanes).
__global__ void k_mix(const float* __restrict__ xsum,
                      const float* __restrict__ cw, const float* __restrict__ cb,
                      const float* __restrict__ dw, const float* __restrict__ db,
                      float* __restrict__ mix) {
    const int b = blockIdx.x, tid = threadIdx.x;
    __shared__ __align__(16) float sxm[256];
    __shared__ __align__(16) float spool[256];
    __shared__ float sl[8];
    sxm[tid] = xsum[b * 256 + tid] * (1.0f / P_);
    __syncthreads();
    {
        float a = cb[tid];
        const float4* cwr = (const float4*)(cw + (size_t)tid * 256);
        const float4* xv4 = (const float4*)sxm;
#pragma unroll 8
        for (int c = 0; c < 64; ++c) {
            const float4 wv = cwr[c];
            const float4 xv = xv4[c];
            a += wv.x * xv.x + wv.y * xv.y + wv.z * xv.z + wv.w * xv.w;
        }
        spool[tid] = a;
    }
    __syncthreads();
    if (tid < 64) {
        const int e = tid >> 3, dl = tid & 7;
        float part = 0.f;
#pragma unroll 4
        for (int d = dl; d < 256; d += 8) part += dw[e * 256 + d] * spool[d];
        part += __shfl_down(part, 4, 64);
        part += __shfl_down(part, 2, 64);
        part += __shfl_down(part, 1, 64);
        if (dl == 0) sl[e] = part + db[e];
    }
    __syncthreads();
    if (tid < 8) {
        float m = sl[0];
        for (int e = 1; e < 8; ++e) m = fmaxf(m, sl[e]);
        float den = 0.f;
        for (int e = 0; e < 8; ++e) den += __expf(sl[e] - m);
        mix[b * 8 + tid] = __expf(sl[tid] - m) / den;
    }
}

// ---------- k_mixkern: Wg[b][o][t][ic] = bf16( sum_e mix[b][e] * KE[e][o][ic][t] ) ----------
// Coalesced: block = (o, ic-half); stage 8 x 1152 contiguous floats in LDS via float4.
// 1152 floats = 288 float4 per e (NOT 576 — round-2 bug overran LDS by 2x).
__global__ void k_mixkern(const float* __restrict__ KE, const float* __restrict__ mix,
                          unsigned short* __restrict__ Wg) {
    const int o    = blockIdx.x >> 1;
    const int half = blockIdx.x & 1;
    const int ic0  = half << 7;
    const int tid  = threadIdx.x;
    __shared__ __align__(16) float s[8][1152];     // 36.9 KB
    __shared__ float smix[128];
    if (tid < 128) smix[tid] = mix[tid];
#pragma unroll
    for (int e = 0; e < 8; ++e) {
        const float4* src = (const float4*)(KE + (size_t)(e * 256 + o) * 2304 + ic0 * 9);
        float4* dst = (float4*)s[e];
        dst[tid] = src[tid];                         // float4 0..255
        if (tid < 32) dst[256 + tid] = src[256 + tid];  // float4 256..287 (= 1152 floats)
    }
    __syncthreads();
    const int icl = tid & 127;
    const int b0  = (tid >> 7) << 3;     // 0 or 8
#pragma unroll
    for (int t = 0; t < 9; ++t) {
        float v[8];
#pragma unroll
        for (int e = 0; e < 8; ++e) v[e] = s[e][icl * 9 + t];
#pragma unroll
        for (int bb = 0; bb < 8; ++bb) {
            const int b = b0 + bb;
            float acc = 0.f;
#pragma unroll
            for (int e = 0; e < 8; ++e) acc += smix[b * 8 + e] * v[e];
            Wg[((size_t)(b * 256 + o) * 9 + t) * 256 + ic0 + icl] = f2bf(acc);
        }
    }
}

// ---------- k_gemm: implicit-im2col bf16 MFMA GEMM (round-0 proven structure) ----------
// Per block: sample b, 128 output channels, 128 pixels (2 rows x 64).
// K = 9 taps * 256 ch = 2304, BK = 64. A = Wg[b][o][k], B^T = Xp pixel rows.
// XCD-pinned: b is derived from bid&7 so each sample's 64 blocks share one L2.
// LDS chunk-slot XOR swizzle (slot = chunk ^ (row&7)) applied on the *global
// source* side of global_load_lds, so fragment ds_read_b128 is conflict-free.
// 32 KB LDS -> 4 blocks/CU co-resident; inter-block overlap hides the barrier
// drain (m114). Explicit dbuf measured WORSE (round-1: 103 vs 91 us).
__global__ __launch_bounds__(256) void k_gemm(const unsigned short* __restrict__ Wg,
                                              const unsigned short* __restrict__ Xp,
                                              float* __restrict__ out) {
    __shared__ __align__(16) unsigned short lA[128 * 64];
    __shared__ __align__(16) unsigned short lB[128 * 64];
    const int tid = threadIdx.x;
    const int bid = blockIdx.x;
    const int xcd = bid & 7;
    const int g   = bid >> 3;
    const int b   = xcd + ((g >> 6) << 3);   // all 64 blocks of sample b on one XCD
    const int rem = g & 63;
    const int ot  = rem & 1;
    const int rp  = rem >> 1;
    const int o0  = ot << 7;
    const int h0  = rp << 1;

    const int wid  = tid >> 6;
    const int lane = tid & 63;
    const int wm   = wid >> 1;
    const int wn   = wid & 1;
    const int ql   = lane & 15;
    const int quad = lane >> 4;
    const int sw   = ql & 7;      // read-side swizzle key (= row&7 of fragment row)

    const int srow = tid >> 3;    // 0..31
    const int sseg = tid & 7;     // 0..7  (LDS slot this thread fills)
    const int csrc = sseg ^ (srow & 7);   // global chunk that belongs in this slot

    f32x4 acc[4][4];
#pragma unroll
    for (int i = 0; i < 4; ++i)
#pragma unroll
        for (int j = 0; j < 4; ++j) acc[i][j] = (f32x4)0.0f;

    char* lAb = (char*)lA;
    char* lBb = (char*)lB;
    // A element index: ((b*256 + o0 + srow + 32j)*9 + t)*256 + kc*64 + csrc*8
    const size_t abase = (size_t)(b * 256 + o0 + srow) * 9 * 256 + csrc * 8;

    for (int t = 0; t < 9; ++t) {
        const int kh = t / 3;
        const int kw = t - kh * 3;
        for (int kc = 0; kc < 4; ++kc) {
#pragma unroll
            for (int j = 0; j < 4; ++j) {
                const unsigned short* ga = Wg + abase + (size_t)j * 32 * 9 * 256
                                           + (size_t)t * 256 + kc * 64;
                async_load16(ga, lAb + tid * 16 + j * 4096);
            }
#pragma unroll
            for (int j = 0; j < 4; ++j) {
                const int pix = srow + 32 * j;
                const int pr  = pix >> 6;
                const int w   = pix & 63;
                const unsigned short* gb = Xp
                    + ((size_t)((b * HP_ + h0 + pr + kh) * HP_ + (w + kw)) << 8)
                    + kc * 64 + csrc * 8;
                async_load16(gb, lBb + tid * 16 + j * 4096);
            }
            __syncthreads();
#pragma unroll
            for (int kk = 0; kk < 2; ++kk) {
                bf16x8 af[4], bv[4];
#pragma unroll
                for (int mi = 0; mi < 4; ++mi)
                    af[mi] = *(const bf16x8*)(lAb + (wm * 64 + mi * 16 + ql) * 128
                                              + ((((kk << 2) | quad) ^ sw) << 4));
#pragma unroll
                for (int ni = 0; ni < 4; ++ni)
                    bv[ni] = *(const bf16x8*)(lBb + (wn * 64 + ni * 16 + ql) * 128
                                              + ((((kk << 2) | quad) ^ sw) << 4));
#pragma unroll
                for (int mi = 0; mi < 4; ++mi)
#pragma unroll
                    for (int ni = 0; ni < 4; ++ni)
                        acc[mi][ni] = __builtin_amdgcn_mfma_f32_16x16x32_bf16(
                            af[mi], bv[ni], acc[mi][ni], 0, 0, 0);
            }
            __syncthreads();
        }
    }

    // Epilogue: C/D layout col=lane&15 (pixel), row=quad*4+reg (o)
    const int h = h0 + wn;
#pragma unroll
    for (int mi = 0; mi < 4; ++mi) {
        const int o = o0 + wm * 64 + mi * 16 + quad * 4;
#pragma unroll
        for (int ni = 0; ni < 4; ++ni) {
            const int w = ni * 16 + ql;
            float* po = out + ((size_t)(b * 256 + o) << 12) + (h << 6) + w;
#pragma unroll
            for (int r = 0; r < 4; ++r) po[(size_t)r << 12] = acc[mi][ni][r];
        }
    }
}

// ---------- launch ----------
extern "C" void kernel_launch(void* const* d_in, const int* in_sizes, int n_in,
                              void* d_out, int out_size, void* d_ws, size_t ws_size,
                              hipStream_t stream) {
    const float* x  = (const float*)d_in[0];
    const float* KE = (const float*)d_in[1];
    const float* cw = (const float*)d_in[2];
    const float* cb = (const float*)d_in[3];
    const float* dw = (const float*)d_in[4];
    const float* db = (const float*)d_in[5];
    float* out = (float*)d_out;

    char* ws = (char*)d_ws;
    float* xsum           = (float*)(ws + 0);            // 16*256*4    = 16 KB
    float* mix            = (float*)(ws + 16384);        // 16*8*4      = 512 B
    unsigned short* Wg    = (unsigned short*)(ws + 32768);            // 18.87 MB
    unsigned short* Xp    = (unsigned short*)(ws + 32768 + 18874368); // 35.68 MB

    hipMemsetAsync(xsum, 0, B_ * C_ * sizeof(float), stream);
    k_xpose  <<<dim3(B_ * H_ * 4),    dim3(256), 0, stream>>>(x, Xp, xsum);
    k_mix    <<<dim3(B_),             dim3(256), 0, stream>>>(xsum, cw, cb, dw, db, mix);
    k_mixkern<<<dim3(C_ * 2),         dim3(256), 0, stream>>>(KE, mix, Wg);
    k_gemm   <<<dim3(B_ * 2 * 32),    dim3(256), 0, stream>>>(Wg, Xp, out);
}

// Round 4
// 253.500 us; speedup vs baseline: 1.0771x; 1.0218x over previous
//
#include <hip/hip_runtime.h>
#include <stdint.h>

// Problem constants
#define B_  16
#define C_  256
#define H_  64
#define W_  64
#define P_  4096      // H*W
#define E_  8
#define HP_ 66        // padded spatial (64 + 2)

typedef __bf16 bf16x8 __attribute__((ext_vector_type(8)));
typedef float  f32x4  __attribute__((ext_vector_type(4)));

// ---------- helpers ----------
__device__ __forceinline__ unsigned short f2bf(float f) {
    union { float f; unsigned int u; } v; v.f = f;
    unsigned int u = v.u;
    unsigned int r = (u + 0x7fffu + ((u >> 16) & 1u)) >> 16;  // RNE
    return (unsigned short)r;
}

__device__ __forceinline__ void async_load16(const void* g, void* l) {
    __builtin_amdgcn_global_load_lds(
        (const __attribute__((address_space(1))) void*)g,
        (__attribute__((address_space(3))) void*)l, 16, 0, 0);
}

// ---------- k_xpose: Xp[b][h+1][w+1][c] = bf16(x[b][c][h][w]) + fused channel-sum
//            + fused pad-border zeroing (blocks 0..519 also zero a border slice) ----------
__global__ void k_xpose(const float* __restrict__ x, unsigned short* __restrict__ Xp,
                        float* __restrict__ xsum) {
    const int bid = blockIdx.x;       // 16 * 64 * 4
    const int tid = threadIdx.x;

    // Fused border zeroing (was k_border): disjoint from interior writes below.
    if (bid < 520) {
        const int gid = bid * 256 + tid;               // 0..133119
        const int pix = gid >> 5;                      // 0..4159 (16*260)
        const int chunk = gid & 31;
        const int bb = pix / 260;
        const int j = pix - bb * 260;
        int h, w;
        if (j < 66)       { h = 0;  w = j; }
        else if (j < 132) { h = 65; w = j - 66; }
        else { int jj = j - 132; h = 1 + (jj & 63); w = (jj < 64) ? 0 : 65; }
        const uint4 z = {0u, 0u, 0u, 0u};
        *(uint4*)(Xp + ((size_t)((bb * HP_ + h) * HP_ + w) << 8) + chunk * 8) = z;
    }

    const int b  = bid >> 8;
    const int h  = (bid >> 2) & 63;
    const int cg = bid & 3;
    const int c0 = cg << 6;
    __shared__ float tile[64][65];
    {
        const int ci = tid >> 2, wseg = tid & 3;
        const float* src = x + ((size_t)(b * 256 + c0 + ci) << 12) + (h << 6) + wseg * 16;
        float s = 0.f;
#pragma unroll
        for (int i = 0; i < 4; ++i) {
            float4 v = *(const float4*)(src + i * 4);
            tile[ci][wseg * 16 + i * 4 + 0] = v.x;
            tile[ci][wseg * 16 + i * 4 + 1] = v.y;
            tile[ci][wseg * 16 + i * 4 + 2] = v.z;
            tile[ci][wseg * 16 + i * 4 + 3] = v.w;
            s += v.x + v.y + v.z + v.w;
        }
        // reduce the 4 wseg lanes (consecutive) and add to channel sum
        s += __shfl_down(s, 1, 64);
        s += __shfl_down(s, 2, 64);
        if ((tid & 3) == 0) atomicAdd(&xsum[b * 256 + c0 + ci], s);
    }
    __syncthreads();
    {
        const int w = tid >> 2, cs = tid & 3;
        unsigned short ov[16] __attribute__((aligned(16)));
#pragma unroll
        for (int k = 0; k < 16; ++k) ov[k] = f2bf(tile[cs * 16 + k][w]);
        unsigned short* dst = Xp + ((size_t)((b * HP_ + h + 1) * HP_ + (w + 1)) << 8) + c0 + cs * 16;
        ((uint4*)dst)[0] = ((const uint4*)ov)[0];
        ((uint4*)dst)[1] = ((const uint4*)ov)[1];
    }
}

// ---------- k_mix: mix[b][e] = softmax_e(dense(conv_w @ xmean + cb) + db) ----------
__global__ void k_mix(const float* __restrict__ xsum,
                      const float* __restrict__ cw, const float* __restrict__ cb,
                      const float* __restrict__ dw, const float* __restrict__ db,
                      float* __restrict__ mix) {
    const int b = blockIdx.x, tid = threadIdx.x;
    __shared__ __align__(16) float sxm[256];
    __shared__ __align__(16) float spool[256];
    __shared__ float sl[8];
    sxm[tid] = xsum[b * 256 + tid] * (1.0f / P_);
    __syncthreads();
    {
        float a = cb[tid];
        const float4* cwr = (const float4*)(cw + (size_t)tid * 256);
        const float4* xv4 = (const float4*)sxm;
#pragma unroll 8
        for (int c = 0; c < 64; ++c) {
            const float4 wv = cwr[c];
            const float4 xv = xv4[c];
            a += wv.x * xv.x + wv.y * xv.y + wv.z * xv.z + wv.w * xv.w;
        }
        spool[tid] = a;
    }
    __syncthreads();
    if (tid < 64) {
        const int e = tid >> 3, dl = tid & 7;
        float part = 0.f;
#pragma unroll 4
        for (int d = dl; d < 256; d += 8) part += dw[e * 256 + d] * spool[d];
        part += __shfl_down(part, 4, 64);
        part += __shfl_down(part, 2, 64);
        part += __shfl_down(part, 1, 64);
        if (dl == 0) sl[e] = part + db[e];
    }
    __syncthreads();
    if (tid < 8) {
        float m = sl[0];
        for (int e = 1; e < 8; ++e) m = fmaxf(m, sl[e]);
        float den = 0.f;
        for (int e = 0; e < 8; ++e) den += __expf(sl[e] - m);
        mix[b * 8 + tid] = __expf(sl[tid] - m) / den;
    }
}

// ---------- k_mixkern: Wg[b][o][t][ic] = bf16( sum_e mix[b][e] * KE[e][o][ic][t] ) ----------
__global__ void k_mixkern(const float* __restrict__ KE, const float* __restrict__ mix,
                          unsigned short* __restrict__ Wg) {
    const int o    = blockIdx.x >> 1;
    const int half = blockIdx.x & 1;
    const int ic0  = half << 7;
    const int tid  = threadIdx.x;
    __shared__ __align__(16) float s[8][1152];     // 36.9 KB
    __shared__ float smix[128];
    if (tid < 128) smix[tid] = mix[tid];
#pragma unroll
    for (int e = 0; e < 8; ++e) {
        const float4* src = (const float4*)(KE + (size_t)(e * 256 + o) * 2304 + ic0 * 9);
        float4* dst = (float4*)s[e];
        dst[tid] = src[tid];                         // float4 0..255
        if (tid < 32) dst[256 + tid] = src[256 + tid];  // float4 256..287 (= 1152 floats)
    }
    __syncthreads();
    const int icl = tid & 127;
    const int b0  = (tid >> 7) << 3;     // 0 or 8
#pragma unroll
    for (int t = 0; t < 9; ++t) {
        float v[8];
#pragma unroll
        for (int e = 0; e < 8; ++e) v[e] = s[e][icl * 9 + t];
#pragma unroll
        for (int bb = 0; bb < 8; ++bb) {
            const int b = b0 + bb;
            float acc = 0.f;
#pragma unroll
            for (int e = 0; e < 8; ++e) acc += smix[b * 8 + e] * v[e];
            Wg[((size_t)(b * 256 + o) * 9 + t) * 256 + ic0 + icl] = f2bf(acc);
        }
    }
}

// ---------- k_gemm: 256x256-tile 8-wave 8-phase counted-vmcnt MFMA GEMM (T3+T4+T5) ----------
// Per block: sample b, ALL 256 o, 256 pixels (4 rows x 64). 512 thr = 8 waves (2M x 4N).
// K = 2304, BK = 64 -> 36 K-tiles, 18 iterations x 8 phases. Grid = 256 blocks = 1/CU.
// LDS: 4 parity-fixed 32KB slots: L[0]=A-even, L[1]=A-odd, L[2]=B-even, L[3]=B-odd.
// Phase: {4-or-8 ds_read_b128 | prefetch issue} -> s_barrier -> lgkmcnt(0) ->
//        setprio(1) 16 MFMA setprio(0) -> [vmcnt(4) @Ph4/Ph8] -> s_barrier.
// Prefetch ledger (iter i): Ph1: A(2i+1)->L[1]  (slot last read prev Ph8)
//                           Ph4: B(2i+2)->L[2]  (last read Ph3), vmcnt(4)
//                           Ph5: A(2i+2)->L[0]  (last read Ph4)
//                           Ph8: B(2i+3)->L[3]  (last read Ph7), vmcnt(4)
// vmcnt(4)@Ph4 leaves only Ph4's 4 loads pending -> A(2i+1) landed before Ph5 reads.
// vmcnt(4)@Ph8 leaves only Ph8's 4 -> A/B(2i+2) landed before next Ph1. Tail i=17:
// vmcnt(0)@Ph4 (counted check vacuous there). Chunk-XOR swizzle as round-0 (0 conflicts).
__global__ __launch_bounds__(512, 2) void k_gemm(const unsigned short* __restrict__ Wg,
                                                 const unsigned short* __restrict__ Xp,
                                                 float* __restrict__ out) {
    __shared__ __align__(16) unsigned short L[4][16384];   // 128 KB
    const int tid = threadIdx.x;
    const int bid = blockIdx.x;
    const int xcd = bid & 7;
    const int g   = bid >> 3;            // 0..31
    const int b   = xcd + ((g >> 4) << 3);   // samples {xcd, xcd+8} share one XCD L2
    const int tile = g & 15;
    const int h0  = tile << 2;

    const int wid  = tid >> 6;           // 0..7
    const int lane = tid & 63;
    const int wm   = wid >> 2;           // 0..1: o-half (128 rows)
    const int wn   = wid & 3;            // 0..3: pixel row (64 pixels)
    const int ql   = lane & 15;
    const int quad = lane >> 4;
    const int sw   = ql & 7;             // read-side swizzle key (= row&7)

    const int srow = tid >> 3;           // 0..63
    const int csrc = (tid & 7) ^ (srow & 7);   // global chunk for this thread's LDS slot

    f32x4 acc[8][4];
#pragma unroll
    for (int i = 0; i < 8; ++i)
#pragma unroll
        for (int j = 0; j < 4; ++j) acc[i][j] = (f32x4)0.0f;

    // Stage full A-tile (256 o x 64 k) of K-tile s into L[P]. 4 x 16B per thread.
    auto stageA = [&](int s, int P) {
        const int t = s >> 2, kc = s & 3;
        const unsigned short* ga = Wg + ((size_t)(b * 256 + srow) * 9 + t) * 256
                                   + kc * 64 + csrc * 8;
#pragma unroll
        for (int j = 0; j < 4; ++j)
            async_load16(ga + (size_t)j * 64 * 9 * 256, (char*)L[P] + tid * 16 + j * 8192);
    };
    // Stage full B-tile (256 pixels x 64 k): row = srow + 64j -> pr=j, w=srow.
    auto stageB = [&](int s, int P) {
        const int t = s >> 2, kc = s & 3;
        const int kh = t / 3, kw = t - kh * 3;
#pragma unroll
        for (int j = 0; j < 4; ++j)
            async_load16(Xp + (((size_t)((b * HP_ + h0 + j + kh) * HP_ + (srow + kw))) << 8)
                             + kc * 64 + csrc * 8,
                         (char*)L[2 + P] + tid * 16 + j * 8192);
    };

    bf16x8 af[4], bv[4];

#define PH(AP, BP, KK, MH, READB, PREF_STMT, VM_STMT)                              \
    do {                                                                           \
        _Pragma("unroll")                                                          \
        for (int r_ = 0; r_ < 4; ++r_)                                             \
            af[r_] = *(const bf16x8*)((const char*)L[AP]                           \
                     + (wm * 128 + ((MH) * 4 + r_) * 16 + ql) * 128                \
                     + (((((KK) << 2) | quad) ^ sw) << 4));                        \
        if (READB) {                                                               \
            _Pragma("unroll")                                                      \
            for (int r_ = 0; r_ < 4; ++r_)                                         \
                bv[r_] = *(const bf16x8*)((const char*)L[BP]                       \
                         + (wn * 64 + r_ * 16 + ql) * 128                          \
                         + (((((KK) << 2) | quad) ^ sw) << 4));                    \
        }                                                                          \
        PREF_STMT;                                                                 \
        asm volatile("s_barrier" ::: "memory");                                    \
        asm volatile("s_waitcnt lgkmcnt(0)" ::: "memory");                         \
        __builtin_amdgcn_s_setprio(1);                                             \
        _Pragma("unroll")                                                          \
        for (int r_ = 0; r_ < 4; ++r_)                                             \
            _Pragma("unroll")                                                      \
            for (int n_ = 0; n_ < 4; ++n_)                                         \
                acc[(MH) * 4 + r_][n_] = __builtin_amdgcn_mfma_f32_16x16x32_bf16(  \
                    af[r_], bv[n_], acc[(MH) * 4 + r_][n_], 0, 0, 0);              \
        __builtin_amdgcn_s_setprio(0);                                             \
        VM_STMT;                                                                   \
        asm volatile("s_barrier" ::: "memory");                                    \
    } while (0)

    // Prologue: A(0)->L[0], B(0)->L[2], B(1)->L[3]; A(1) comes from iter-0 Ph1.
    stageA(0, 0); stageB(0, 0); stageB(1, 1);
    asm volatile("s_waitcnt vmcnt(4)" ::: "memory");   // A(0),B(0) landed; B(1) may pend
    asm volatile("s_barrier" ::: "memory");

    for (int i = 0; i < 18; ++i) {
        const int sE = 2 * i;
        const int sO = sE + 1;
        const bool pf = (i < 17);
        // ---- even tile (parity 0) ----
        PH(0, 2, 0, 0, 1, stageA(sO, 1), ((void)0));
        PH(0, 2, 0, 1, 0, ((void)0), ((void)0));
        PH(0, 2, 1, 0, 1, ((void)0), ((void)0));
        PH(0, 2, 1, 1, 0,
           if (pf) stageB(sE + 2, 0),
           if (pf) { asm volatile("s_waitcnt vmcnt(4)" ::: "memory"); }
           else    { asm volatile("s_waitcnt vmcnt(0)" ::: "memory"); });
        // ---- odd tile (parity 1) ----
        PH(1, 3, 0, 0, 1, if (pf) stageA(sE + 2, 0), ((void)0));
        PH(1, 3, 0, 1, 0, ((void)0), ((void)0));
        PH(1, 3, 1, 0, 1, ((void)0), ((void)0));
        PH(1, 3, 1, 1, 0,
           if (pf) stageB(sO + 2, 1),
           if (pf) { asm volatile("s_waitcnt vmcnt(4)" ::: "memory"); });
    }
#undef PH

    // Epilogue: C/D layout col=lane&15 (pixel), row=quad*4+reg (o)
#pragma unroll
    for (int m = 0; m < 8; ++m) {
        const int o = wm * 128 + m * 16 + quad * 4;
#pragma unroll
        for (int n = 0; n < 4; ++n) {
            const int w = n * 16 + ql;
            float* po = out + ((size_t)(b * 256 + o) << 12) + ((h0 + wn) << 6) + w;
#pragma unroll
            for (int r = 0; r < 4; ++r) po[(size_t)r << 12] = acc[m][n][r];
        }
    }
}

// ---------- launch ----------
extern "C" void kernel_launch(void* const* d_in, const int* in_sizes, int n_in,
                              void* d_out, int out_size, void* d_ws, size_t ws_size,
                              hipStream_t stream) {
    const float* x  = (const float*)d_in[0];
    const float* KE = (const float*)d_in[1];
    const float* cw = (const float*)d_in[2];
    const float* cb = (const float*)d_in[3];
    const float* dw = (const float*)d_in[4];
    const float* db = (const float*)d_in[5];
    float* out = (float*)d_out;

    char* ws = (char*)d_ws;
    float* xsum           = (float*)(ws + 0);            // 16*256*4    = 16 KB
    float* mix            = (float*)(ws + 16384);        // 16*8*4      = 512 B
    unsigned short* Wg    = (unsigned short*)(ws + 32768);            // 18.87 MB
    unsigned short* Xp    = (unsigned short*)(ws + 32768 + 18874368); // 35.68 MB

    hipMemsetAsync(xsum, 0, B_ * C_ * sizeof(float), stream);
    k_xpose  <<<dim3(B_ * H_ * 4),    dim3(256), 0, stream>>>(x, Xp, xsum);
    k_mix    <<<dim3(B_),             dim3(256), 0, stream>>>(xsum, cw, cb, dw, db, mix);
    k_mixkern<<<dim3(C_ * 2),         dim3(256), 0, stream>>>(KE, mix, Wg);
    k_gemm   <<<dim3(256),            dim3(512), 0, stream>>>(Wg, Xp, out);
}

// Round 5
// 248.222 us; speedup vs baseline: 1.1000x; 1.0213x over previous
//
#include <hip/hip_runtime.h>
#include <stdint.h>

// Problem constants
#define B_  16
#define C_  256
#define H_  64
#define W_  64
#define P_  4096      // H*W
#define E_  8
#define HP_ 66        // padded spatial (64 + 2)

typedef __bf16 bf16x8 __attribute__((ext_vector_type(8)));
typedef float  f32x4  __attribute__((ext_vector_type(4)));

// ---------- helpers ----------
__device__ __forceinline__ unsigned short f2bf(float f) {
    union { float f; unsigned int u; } v; v.f = f;
    unsigned int u = v.u;
    unsigned int r = (u + 0x7fffu + ((u >> 16) & 1u)) >> 16;  // RNE
    return (unsigned short)r;
}

__device__ __forceinline__ void async_load16(const void* g, void* l) {
    __builtin_amdgcn_global_load_lds(
        (const __attribute__((address_space(1))) void*)g,
        (__attribute__((address_space(3))) void*)l, 16, 0, 0);
}

// ---------- k_xpose: Xp[b][h+1][w+1][c] = bf16(x[b][c][h][w]) + fused channel-sum
//            + fused pad-border zeroing (blocks 0..519 also zero a border slice) ----------
__global__ void k_xpose(const float* __restrict__ x, unsigned short* __restrict__ Xp,
                        float* __restrict__ xsum) {
    const int bid = blockIdx.x;       // 16 * 64 * 4
    const int tid = threadIdx.x;

    // Fused border zeroing (was k_border): disjoint from interior writes below.
    if (bid < 520) {
        const int gid = bid * 256 + tid;               // 0..133119
        const int pix = gid >> 5;                      // 0..4159 (16*260)
        const int chunk = gid & 31;
        const int bb = pix / 260;
        const int j = pix - bb * 260;
        int h, w;
        if (j < 66)       { h = 0;  w = j; }
        else if (j < 132) { h = 65; w = j - 66; }
        else { int jj = j - 132; h = 1 + (jj & 63); w = (jj < 64) ? 0 : 65; }
        const uint4 z = {0u, 0u, 0u, 0u};
        *(uint4*)(Xp + ((size_t)((bb * HP_ + h) * HP_ + w) << 8) + chunk * 8) = z;
    }

    const int b  = bid >> 8;
    const int h  = (bid >> 2) & 63;
    const int cg = bid & 3;
    const int c0 = cg << 6;
    __shared__ float tile[64][65];
    {
        const int ci = tid >> 2, wseg = tid & 3;
        const float* src = x + ((size_t)(b * 256 + c0 + ci) << 12) + (h << 6) + wseg * 16;
        float s = 0.f;
#pragma unroll
        for (int i = 0; i < 4; ++i) {
            float4 v = *(const float4*)(src + i * 4);
            tile[ci][wseg * 16 + i * 4 + 0] = v.x;
            tile[ci][wseg * 16 + i * 4 + 1] = v.y;
            tile[ci][wseg * 16 + i * 4 + 2] = v.z;
            tile[ci][wseg * 16 + i * 4 + 3] = v.w;
            s += v.x + v.y + v.z + v.w;
        }
        // reduce the 4 wseg lanes (consecutive) and add to channel sum
        s += __shfl_down(s, 1, 64);
        s += __shfl_down(s, 2, 64);
        if ((tid & 3) == 0) atomicAdd(&xsum[b * 256 + c0 + ci], s);
    }
    __syncthreads();
    {
        const int w = tid >> 2, cs = tid & 3;
        unsigned short ov[16] __attribute__((aligned(16)));
#pragma unroll
        for (int k = 0; k < 16; ++k) ov[k] = f2bf(tile[cs * 16 + k][w]);
        unsigned short* dst = Xp + ((size_t)((b * HP_ + h + 1) * HP_ + (w + 1)) << 8) + c0 + cs * 16;
        ((uint4*)dst)[0] = ((const uint4*)ov)[0];
        ((uint4*)dst)[1] = ((const uint4*)ov)[1];
    }
}

// ---------- k_mix: mix[b][e] = softmax_e(dense(conv_w @ xmean + cb) + db) ----------
__global__ void k_mix(const float* __restrict__ xsum,
                      const float* __restrict__ cw, const float* __restrict__ cb,
                      const float* __restrict__ dw, const float* __restrict__ db,
                      float* __restrict__ mix) {
    const int b = blockIdx.x, tid = threadIdx.x;
    __shared__ __align__(16) float sxm[256];
    __shared__ __align__(16) float spool[256];
    __shared__ float sl[8];
    sxm[tid] = xsum[b * 256 + tid] * (1.0f / P_);
    __syncthreads();
    {
        float a = cb[tid];
        const float4* cwr = (const float4*)(cw + (size_t)tid * 256);
        const float4* xv4 = (const float4*)sxm;
#pragma unroll 8
        for (int c = 0; c < 64; ++c) {
            const float4 wv = cwr[c];
            const float4 xv = xv4[c];
            a += wv.x * xv.x + wv.y * xv.y + wv.z * xv.z + wv.w * xv.w;
        }
        spool[tid] = a;
    }
    __syncthreads();
    if (tid < 64) {
        const int e = tid >> 3, dl = tid & 7;
        float part = 0.f;
#pragma unroll 4
        for (int d = dl; d < 256; d += 8) part += dw[e * 256 + d] * spool[d];
        part += __shfl_down(part, 4, 64);
        part += __shfl_down(part, 2, 64);
        part += __shfl_down(part, 1, 64);
        if (dl == 0) sl[e] = part + db[e];
    }
    __syncthreads();
    if (tid < 8) {
        float m = sl[0];
        for (int e = 1; e < 8; ++e) m = fmaxf(m, sl[e]);
        float den = 0.f;
        for (int e = 0; e < 8; ++e) den += __expf(sl[e] - m);
        mix[b * 8 + tid] = __expf(sl[tid] - m) / den;
    }
}

// ---------- k_mixkern: Wg[b][o][t][ic] = bf16( sum_e mix[b][e] * KE[e][o][ic][t] ) ----------
__global__ void k_mixkern(const float* __restrict__ KE, const float* __restrict__ mix,
                          unsigned short* __restrict__ Wg) {
    const int o    = blockIdx.x >> 1;
    const int half = blockIdx.x & 1;
    const int ic0  = half << 7;
    const int tid  = threadIdx.x;
    __shared__ __align__(16) float s[8][1152];     // 36.9 KB
    __shared__ float smix[128];
    if (tid < 128) smix[tid] = mix[tid];
#pragma unroll
    for (int e = 0; e < 8; ++e) {
        const float4* src = (const float4*)(KE + (size_t)(e * 256 + o) * 2304 + ic0 * 9);
        float4* dst = (float4*)s[e];
        dst[tid] = src[tid];                         // float4 0..255
        if (tid < 32) dst[256 + tid] = src[256 + tid];  // float4 256..287 (= 1152 floats)
    }
    __syncthreads();
    const int icl = tid & 127;
    const int b0  = (tid >> 7) << 3;     // 0 or 8
#pragma unroll
    for (int t = 0; t < 9; ++t) {
        float v[8];
#pragma unroll
        for (int e = 0; e < 8; ++e) v[e] = s[e][icl * 9 + t];
#pragma unroll
        for (int bb = 0; bb < 8; ++bb) {
            const int b = b0 + bb;
            float acc = 0.f;
#pragma unroll
            for (int e = 0; e < 8; ++e) acc += smix[b * 8 + e] * v[e];
            Wg[((size_t)(b * 256 + o) * 9 + t) * 256 + ic0 + icl] = f2bf(acc);
        }
    }
}

// ---------- k_gemm: 256x256-tile 8-wave 8-phase counted-vmcnt MFMA GEMM ----------
// Round-5 change: ONE barrier per phase (was 2). Phase = {ds_reads; stage-issue;
// [vmcnt]; s_barrier; lgkmcnt(0); setprio(1); 16 MFMA; setprio(0)}.
// Safety ledger (slots L0=A-even L1=A-odd L2=B-even L3=B-odd):
//   stage X->slot is always AFTER the barrier of the phase holding the slot's
//   last reads: Ph1->L1 (last read prev Ph8 < bar_ph8·prev); Ph4->L2 (last read
//   Ph3 < bar_ph3); Ph5->L0 (Ph4 < bar_ph4); Ph8->L3 (Ph7 < bar_ph7).
//   Reads and stages both live between consecutive barriers and touch disjoint
//   slots, so cross-wave order is enforced by the single barrier.
// Landing: Ph4 vmcnt(4): outstanding {prevPh8 B(2i+1),Ph1 A(2i+1),Ph4 B(2i+2)}
//   =12 -> 4 => A(2i+1),B(2i+1) landed before bar_ph4 < Ph5 reads of L1/L3.
//   Ph8 vmcnt(4): {Ph5 A(2i+2),Ph8 B(2i+3)}=8 -> 4 (and B(2i+2) older) => L0/L2
//   ready before next Ph1. Tail i=17: Ph4 vmcnt(0) drains A(35),B(35).
// MFMA (register-only) may drift past the barrier — correctness-neutral.
__global__ __launch_bounds__(512, 2) void k_gemm(const unsigned short* __restrict__ Wg,
                                                 const unsigned short* __restrict__ Xp,
                                                 float* __restrict__ out) {
    __shared__ __align__(16) unsigned short L[4][16384];   // 128 KB
    const int tid = threadIdx.x;
    const int bid = blockIdx.x;
    const int xcd = bid & 7;
    const int g   = bid >> 3;            // 0..31
    const int b   = xcd + ((g >> 4) << 3);   // samples {xcd, xcd+8} share one XCD L2
    const int tile = g & 15;
    const int h0  = tile << 2;

    const int wid  = tid >> 6;           // 0..7
    const int lane = tid & 63;
    const int wm   = wid >> 2;           // 0..1: o-half (128 rows)
    const int wn   = wid & 3;            // 0..3: pixel row (64 pixels)
    const int ql   = lane & 15;
    const int quad = lane >> 4;
    const int sw   = ql & 7;             // read-side swizzle key (= row&7)

    const int srow = tid >> 3;           // 0..63
    const int csrc = (tid & 7) ^ (srow & 7);   // global chunk for this thread's LDS slot

    f32x4 acc[8][4];
#pragma unroll
    for (int i = 0; i < 8; ++i)
#pragma unroll
        for (int j = 0; j < 4; ++j) acc[i][j] = (f32x4)0.0f;

    // Stage full A-tile (256 o x 64 k) of K-tile s into L[P]. 4 x 16B per thread.
    auto stageA = [&](int s, int P) {
        const int t = s >> 2, kc = s & 3;
        const unsigned short* ga = Wg + ((size_t)(b * 256 + srow) * 9 + t) * 256
                                   + kc * 64 + csrc * 8;
#pragma unroll
        for (int j = 0; j < 4; ++j)
            async_load16(ga + (size_t)j * 64 * 9 * 256, (char*)L[P] + tid * 16 + j * 8192);
    };
    // Stage full B-tile (256 pixels x 64 k): row = srow + 64j -> pr=j, w=srow.
    auto stageB = [&](int s, int P) {
        const int t = s >> 2, kc = s & 3;
        const int kh = t / 3, kw = t - kh * 3;
#pragma unroll
        for (int j = 0; j < 4; ++j)
            async_load16(Xp + (((size_t)((b * HP_ + h0 + j + kh) * HP_ + (srow + kw))) << 8)
                             + kc * 64 + csrc * 8,
                         (char*)L[2 + P] + tid * 16 + j * 8192);
    };

    bf16x8 af[4], bv[4];

#define PH(AP, BP, KK, MH, READB, PREF_STMT, VM_STMT)                              \
    do {                                                                           \
        _Pragma("unroll")                                                          \
        for (int r_ = 0; r_ < 4; ++r_)                                             \
            af[r_] = *(const bf16x8*)((const char*)L[AP]                           \
                     + (wm * 128 + ((MH) * 4 + r_) * 16 + ql) * 128                \
                     + (((((KK) << 2) | quad) ^ sw) << 4));                        \
        if (READB) {                                                               \
            _Pragma("unroll")                                                      \
            for (int r_ = 0; r_ < 4; ++r_)                                         \
                bv[r_] = *(const bf16x8*)((const char*)L[BP]                       \
                         + (wn * 64 + r_ * 16 + ql) * 128                          \
                         + (((((KK) << 2) | quad) ^ sw) << 4));                    \
        }                                                                          \
        PREF_STMT;                                                                 \
        VM_STMT;                                                                   \
        asm volatile("s_barrier" ::: "memory");                                    \
        asm volatile("s_waitcnt lgkmcnt(0)" ::: "memory");                         \
        __builtin_amdgcn_s_setprio(1);                                             \
        _Pragma("unroll")                                                          \
        for (int r_ = 0; r_ < 4; ++r_)                                             \
            _Pragma("unroll")                                                      \
            for (int n_ = 0; n_ < 4; ++n_)                                         \
                acc[(MH) * 4 + r_][n_] = __builtin_amdgcn_mfma_f32_16x16x32_bf16(  \
                    af[r_], bv[n_], acc[(MH) * 4 + r_][n_], 0, 0, 0);              \
        __builtin_amdgcn_s_setprio(0);                                             \
    } while (0)

    // Prologue: A(0)->L[0], B(0)->L[2], B(1)->L[3]; A(1) comes from iter-0 Ph1.
    stageA(0, 0); stageB(0, 0); stageB(1, 1);
    asm volatile("s_waitcnt vmcnt(4)" ::: "memory");   // A(0),B(0) landed; B(1) may pend
    asm volatile("s_barrier" ::: "memory");

    for (int i = 0; i < 18; ++i) {
        const int sE = 2 * i;
        const int sO = sE + 1;
        const bool pf = (i < 17);
        // ---- even tile (parity 0) ----
        PH(0, 2, 0, 0, 1, stageA(sO, 1), ((void)0));
        PH(0, 2, 0, 1, 0, ((void)0), ((void)0));
        PH(0, 2, 1, 0, 1, ((void)0), ((void)0));
        PH(0, 2, 1, 1, 0,
           if (pf) stageB(sE + 2, 0),
           if (pf) { asm volatile("s_waitcnt vmcnt(4)" ::: "memory"); }
           else    { asm volatile("s_waitcnt vmcnt(0)" ::: "memory"); });
        // ---- odd tile (parity 1) ----
        PH(1, 3, 0, 0, 1, if (pf) stageA(sE + 2, 0), ((void)0));
        PH(1, 3, 0, 1, 0, ((void)0), ((void)0));
        PH(1, 3, 1, 0, 1, ((void)0), ((void)0));
        PH(1, 3, 1, 1, 0,
           if (pf) stageB(sO + 2, 1),
           if (pf) { asm volatile("s_waitcnt vmcnt(4)" ::: "memory"); });
    }
#undef PH

    // Epilogue: C/D layout col=lane&15 (pixel), row=quad*4+reg (o)
#pragma unroll
    for (int m = 0; m < 8; ++m) {
        const int o = wm * 128 + m * 16 + quad * 4;
#pragma unroll
        for (int n = 0; n < 4; ++n) {
            const int w = n * 16 + ql;
            float* po = out + ((size_t)(b * 256 + o) << 12) + ((h0 + wn) << 6) + w;
#pragma unroll
            for (int r = 0; r < 4; ++r) po[(size_t)r << 12] = acc[m][n][r];
        }
    }
}

// ---------- launch ----------
extern "C" void kernel_launch(void* const* d_in, const int* in_sizes, int n_in,
                              void* d_out, int out_size, void* d_ws, size_t ws_size,
                              hipStream_t stream) {
    const float* x  = (const float*)d_in[0];
    const float* KE = (const float*)d_in[1];
    const float* cw = (const float*)d_in[2];
    const float* cb = (const float*)d_in[3];
    const float* dw = (const float*)d_in[4];
    const float* db = (const float*)d_in[5];
    float* out = (float*)d_out;

    char* ws = (char*)d_ws;
    float* xsum           = (float*)(ws + 0);            // 16*256*4    = 16 KB
    float* mix            = (float*)(ws + 16384);        // 16*8*4      = 512 B
    unsigned short* Wg    = (unsigned short*)(ws + 32768);            // 18.87 MB
    unsigned short* Xp    = (unsigned short*)(ws + 32768 + 18874368); // 35.68 MB

    hipMemsetAsync(xsum, 0, B_ * C_ * sizeof(float), stream);
    k_xpose  <<<dim3(B_ * H_ * 4),    dim3(256), 0, stream>>>(x, Xp, xsum);
    k_mix    <<<dim3(B_),             dim3(256), 0, stream>>>(xsum, cw, cb, dw, db, mix);
    k_mixkern<<<dim3(C_ * 2),         dim3(256), 0, stream>>>(KE, mix, Wg);
    k_gemm   <<<dim3(256),            dim3(512), 0, stream>>>(Wg, Xp, out);
}

// Round 6
// 246.405 us; speedup vs baseline: 1.1081x; 1.0074x over previous
//
#include <hip/hip_runtime.h>
#include <stdint.h>

// Problem constants
#define B_  16
#define C_  256
#define H_  64
#define W_  64
#define P_  4096      // H*W
#define E_  8
#define HP_ 66        // padded spatial (64 + 2)

typedef __bf16 bf16x8 __attribute__((ext_vector_type(8)));
typedef float  f32x4  __attribute__((ext_vector_type(4)));

// ---------- helpers ----------
__device__ __forceinline__ unsigned short f2bf(float f) {
    union { float f; unsigned int u; } v; v.f = f;
    unsigned int u = v.u;
    unsigned int r = (u + 0x7fffu + ((u >> 16) & 1u)) >> 16;  // RNE
    return (unsigned short)r;
}

__device__ __forceinline__ void async_load16(const void* g, void* l) {
    __builtin_amdgcn_global_load_lds(
        (const __attribute__((address_space(1))) void*)g,
        (__attribute__((address_space(3))) void*)l, 16, 0, 0);
}

// ---------- k_xpose: Xp[b][h+1][w+1][c] = bf16(x[b][c][h][w]) + fused channel-sum
//            + fused pad-border zeroing (blocks 0..519 also zero a border slice) ----------
__global__ void k_xpose(const float* __restrict__ x, unsigned short* __restrict__ Xp,
                        float* __restrict__ xsum) {
    const int bid = blockIdx.x;       // 16 * 64 * 4
    const int tid = threadIdx.x;

    // Fused border zeroing (was k_border): disjoint from interior writes below.
    if (bid < 520) {
        const int gid = bid * 256 + tid;               // 0..133119
        const int pix = gid >> 5;                      // 0..4159 (16*260)
        const int chunk = gid & 31;
        const int bb = pix / 260;
        const int j = pix - bb * 260;
        int h, w;
        if (j < 66)       { h = 0;  w = j; }
        else if (j < 132) { h = 65; w = j - 66; }
        else { int jj = j - 132; h = 1 + (jj & 63); w = (jj < 64) ? 0 : 65; }
        const uint4 z = {0u, 0u, 0u, 0u};
        *(uint4*)(Xp + ((size_t)((bb * HP_ + h) * HP_ + w) << 8) + chunk * 8) = z;
    }

    const int b  = bid >> 8;
    const int h  = (bid >> 2) & 63;
    const int cg = bid & 3;
    const int c0 = cg << 6;
    __shared__ float tile[64][65];
    {
        const int ci = tid >> 2, wseg = tid & 3;
        const float* src = x + ((size_t)(b * 256 + c0 + ci) << 12) + (h << 6) + wseg * 16;
        float s = 0.f;
#pragma unroll
        for (int i = 0; i < 4; ++i) {
            float4 v = *(const float4*)(src + i * 4);
            tile[ci][wseg * 16 + i * 4 + 0] = v.x;
            tile[ci][wseg * 16 + i * 4 + 1] = v.y;
            tile[ci][wseg * 16 + i * 4 + 2] = v.z;
            tile[ci][wseg * 16 + i * 4 + 3] = v.w;
            s += v.x + v.y + v.z + v.w;
        }
        // reduce the 4 wseg lanes (consecutive) and add to channel sum
        s += __shfl_down(s, 1, 64);
        s += __shfl_down(s, 2, 64);
        if ((tid & 3) == 0) atomicAdd(&xsum[b * 256 + c0 + ci], s);
    }
    __syncthreads();
    {
        const int w = tid >> 2, cs = tid & 3;
        unsigned short ov[16] __attribute__((aligned(16)));
#pragma unroll
        for (int k = 0; k < 16; ++k) ov[k] = f2bf(tile[cs * 16 + k][w]);
        unsigned short* dst = Xp + ((size_t)((b * HP_ + h + 1) * HP_ + (w + 1)) << 8) + c0 + cs * 16;
        ((uint4*)dst)[0] = ((const uint4*)ov)[0];
        ((uint4*)dst)[1] = ((const uint4*)ov)[1];
    }
}

// ---------- k_mix: mix[b][e] = softmax_e(dense(conv_w @ xmean + cb) + db) ----------
__global__ void k_mix(const float* __restrict__ xsum,
                      const float* __restrict__ cw, const float* __restrict__ cb,
                      const float* __restrict__ dw, const float* __restrict__ db,
                      float* __restrict__ mix) {
    const int b = blockIdx.x, tid = threadIdx.x;
    __shared__ __align__(16) float sxm[256];
    __shared__ __align__(16) float spool[256];
    __shared__ float sl[8];
    sxm[tid] = xsum[b * 256 + tid] * (1.0f / P_);
    __syncthreads();
    {
        float a = cb[tid];
        const float4* cwr = (const float4*)(cw + (size_t)tid * 256);
        const float4* xv4 = (const float4*)sxm;
#pragma unroll 8
        for (int c = 0; c < 64; ++c) {
            const float4 wv = cwr[c];
            const float4 xv = xv4[c];
            a += wv.x * xv.x + wv.y * xv.y + wv.z * xv.z + wv.w * xv.w;
        }
        spool[tid] = a;
    }
    __syncthreads();
    if (tid < 64) {
        const int e = tid >> 3, dl = tid & 7;
        float part = 0.f;
#pragma unroll 4
        for (int d = dl; d < 256; d += 8) part += dw[e * 256 + d] * spool[d];
        part += __shfl_down(part, 4, 64);
        part += __shfl_down(part, 2, 64);
        part += __shfl_down(part, 1, 64);
        if (dl == 0) sl[e] = part + db[e];
    }
    __syncthreads();
    if (tid < 8) {
        float m = sl[0];
        for (int e = 1; e < 8; ++e) m = fmaxf(m, sl[e]);
        float den = 0.f;
        for (int e = 0; e < 8; ++e) den += __expf(sl[e] - m);
        mix[b * 8 + tid] = __expf(sl[tid] - m) / den;
    }
}

// ---------- k_mixkern: Wg[b][o][t][ic] = bf16( sum_e mix[b][e] * KE[e][o][ic][t] ) ----------
__global__ void k_mixkern(const float* __restrict__ KE, const float* __restrict__ mix,
                          unsigned short* __restrict__ Wg) {
    const int o    = blockIdx.x >> 1;
    const int half = blockIdx.x & 1;
    const int ic0  = half << 7;
    const int tid  = threadIdx.x;
    __shared__ __align__(16) float s[8][1152];     // 36.9 KB
    __shared__ float smix[128];
    if (tid < 128) smix[tid] = mix[tid];
#pragma unroll
    for (int e = 0; e < 8; ++e) {
        const float4* src = (const float4*)(KE + (size_t)(e * 256 + o) * 2304 + ic0 * 9);
        float4* dst = (float4*)s[e];
        dst[tid] = src[tid];                         // float4 0..255
        if (tid < 32) dst[256 + tid] = src[256 + tid];  // float4 256..287 (= 1152 floats)
    }
    __syncthreads();
    const int icl = tid & 127;
    const int b0  = (tid >> 7) << 3;     // 0 or 8
#pragma unroll
    for (int t = 0; t < 9; ++t) {
        float v[8];
#pragma unroll
        for (int e = 0; e < 8; ++e) v[e] = s[e][icl * 9 + t];
#pragma unroll
        for (int bb = 0; bb < 8; ++bb) {
            const int b = b0 + bb;
            float acc = 0.f;
#pragma unroll
            for (int e = 0; e < 8; ++e) acc += smix[b * 8 + e] * v[e];
            Wg[((size_t)(b * 256 + o) * 9 + t) * 256 + ic0 + icl] = f2bf(acc);
        }
    }
}

// ---------- k_gemm: 256x256-tile 8-wave MERGED 4-phase counted-vmcnt MFMA GEMM ----------
// Round-6 change: merge phase pairs -> 4 phases/iter, 32 MFMA per phase (was 8x16).
// Halves barrier/lgkm fences (144->72); each phase's 12 ds_read_b128 overlap a
// 1240-cyc MFMA burst instead of 620.
// Phase = {ds_reads(af x8, bv x4); stage-issue; [vmcnt]; s_barrier; lgkmcnt(0);
//          setprio(1); 32 MFMA; setprio(0)}.
// Ledger (L0=A-even L1=A-odd L2=B-even L3=B-odd), iter i, sE=2i, sO=2i+1:
//   P1 kk0 reads L0,L2; stages A(sO)->L1, B(sO)->L3   (last reads prev-P4 < bar)
//   P2 kk1 reads L0,L2; vmcnt(0)  [in-flight = P1's 8, all needed by P3]
//   P3 kk0 reads L1,L3; stages A(sE+2)->L0, B(sE+2)->L2 (last reads P2 < bar)
//   P4 kk1 reads L1,L3; vmcnt(0)  [in-flight = P3's 8, needed by next P1]
// vmcnt(0) here == counted: queue holds exactly next phase's loads (no over-drain).
// Load-to-use cover ~2 phases (~2200 cyc) > 900-cyc HBM miss. Tail i=17: no stage.
// Compiler tracks af/bv <- LDS deps for its own waitcnt (plain C++ derefs).
__global__ __launch_bounds__(512, 2) void k_gemm(const unsigned short* __restrict__ Wg,
                                                 const unsigned short* __restrict__ Xp,
                                                 float* __restrict__ out) {
    __shared__ __align__(16) unsigned short L[4][16384];   // 128 KB
    const int tid = threadIdx.x;
    const int bid = blockIdx.x;
    const int xcd = bid & 7;
    const int g   = bid >> 3;            // 0..31
    const int b   = xcd + ((g >> 4) << 3);   // samples {xcd, xcd+8} share one XCD L2
    const int tile = g & 15;
    const int h0  = tile << 2;

    const int wid  = tid >> 6;           // 0..7
    const int lane = tid & 63;
    const int wm   = wid >> 2;           // 0..1: o-half (128 rows)
    const int wn   = wid & 3;            // 0..3: pixel row (64 pixels)
    const int ql   = lane & 15;
    const int quad = lane >> 4;
    const int sw   = ql & 7;             // read-side swizzle key (= row&7)

    const int srow = tid >> 3;           // 0..63
    const int csrc = (tid & 7) ^ (srow & 7);   // global chunk for this thread's LDS slot

    f32x4 acc[8][4];
#pragma unroll
    for (int i = 0; i < 8; ++i)
#pragma unroll
        for (int j = 0; j < 4; ++j) acc[i][j] = (f32x4)0.0f;

    // Stage full A-tile (256 o x 64 k) of K-tile s into L[P]. 4 x 16B per thread.
    auto stageA = [&](int s, int P) {
        const int t = s >> 2, kc = s & 3;
        const unsigned short* ga = Wg + ((size_t)(b * 256 + srow) * 9 + t) * 256
                                   + kc * 64 + csrc * 8;
#pragma unroll
        for (int j = 0; j < 4; ++j)
            async_load16(ga + (size_t)j * 64 * 9 * 256, (char*)L[P] + tid * 16 + j * 8192);
    };
    // Stage full B-tile (256 pixels x 64 k): row = srow + 64j -> pr=j, w=srow.
    auto stageB = [&](int s, int P) {
        const int t = s >> 2, kc = s & 3;
        const int kh = t / 3, kw = t - kh * 3;
#pragma unroll
        for (int j = 0; j < 4; ++j)
            async_load16(Xp + (((size_t)((b * HP_ + h0 + j + kh) * HP_ + (srow + kw))) << 8)
                             + kc * 64 + csrc * 8,
                         (char*)L[2 + P] + tid * 16 + j * 8192);
    };

    bf16x8 af0[4], af1[4], bv[4];

#define MPH(AP, BP, KK, PREF_STMT, VM_STMT)                                        \
    do {                                                                           \
        _Pragma("unroll")                                                          \
        for (int r_ = 0; r_ < 4; ++r_)                                             \
            af0[r_] = *(const bf16x8*)((const char*)L[AP]                          \
                      + (wm * 128 + r_ * 16 + ql) * 128                            \
                      + (((((KK) << 2) | quad) ^ sw) << 4));                       \
        _Pragma("unroll")                                                          \
        for (int r_ = 0; r_ < 4; ++r_)                                             \
            af1[r_] = *(const bf16x8*)((const char*)L[AP]                          \
                      + (wm * 128 + 64 + r_ * 16 + ql) * 128                       \
                      + (((((KK) << 2) | quad) ^ sw) << 4));                       \
        _Pragma("unroll")                                                          \
        for (int r_ = 0; r_ < 4; ++r_)                                             \
            bv[r_] = *(const bf16x8*)((const char*)L[BP]                           \
                     + (wn * 64 + r_ * 16 + ql) * 128                              \
                     + (((((KK) << 2) | quad) ^ sw) << 4));                        \
        PREF_STMT;                                                                 \
        VM_STMT;                                                                   \
        asm volatile("s_barrier" ::: "memory");                                    \
        asm volatile("s_waitcnt lgkmcnt(0)" ::: "memory");                         \
        __builtin_amdgcn_s_setprio(1);                                             \
        _Pragma("unroll")                                                          \
        for (int r_ = 0; r_ < 4; ++r_)                                             \
            _Pragma("unroll")                                                      \
            for (int n_ = 0; n_ < 4; ++n_)                                         \
                acc[r_][n_] = __builtin_amdgcn_mfma_f32_16x16x32_bf16(             \
                    af0[r_], bv[n_], acc[r_][n_], 0, 0, 0);                        \
        _Pragma("unroll")                                                          \
        for (int r_ = 0; r_ < 4; ++r_)                                             \
            _Pragma("unroll")                                                      \
            for (int n_ = 0; n_ < 4; ++n_)                                         \
                acc[4 + r_][n_] = __builtin_amdgcn_mfma_f32_16x16x32_bf16(         \
                    af1[r_], bv[n_], acc[4 + r_][n_], 0, 0, 0);                    \
        __builtin_amdgcn_s_setprio(0);                                             \
    } while (0)

    // Prologue: A(0)->L[0], B(0)->L[2]; drain; barrier.
    stageA(0, 0); stageB(0, 0);
    asm volatile("s_waitcnt vmcnt(0)" ::: "memory");
    asm volatile("s_barrier" ::: "memory");

    for (int i = 0; i < 18; ++i) {
        const int sE = 2 * i;
        const int sO = sE + 1;
        const bool pf = (i < 17);
        MPH(0, 2, 0, { stageA(sO, 1); stageB(sO, 1); }, ((void)0));
        MPH(0, 2, 1, ((void)0),
            { asm volatile("s_waitcnt vmcnt(0)" ::: "memory"); });
        MPH(1, 3, 0, if (pf) { stageA(sE + 2, 0); stageB(sE + 2, 0); }, ((void)0));
        MPH(1, 3, 1, ((void)0),
            if (pf) { asm volatile("s_waitcnt vmcnt(0)" ::: "memory"); });
    }
#undef MPH

    // Epilogue: C/D layout col=lane&15 (pixel), row=quad*4+reg (o)
#pragma unroll
    for (int m = 0; m < 8; ++m) {
        const int mh = m >> 2, mr = m & 3;           // acc index -> o offset
        const int o = wm * 128 + mh * 64 + mr * 16 + quad * 4;
#pragma unroll
        for (int n = 0; n < 4; ++n) {
            const int w = n * 16 + ql;
            float* po = out + ((size_t)(b * 256 + o) << 12) + ((h0 + wn) << 6) + w;
#pragma unroll
            for (int r = 0; r < 4; ++r) po[(size_t)r << 12] = acc[mh * 4 + mr][n][r];
        }
    }
}

// ---------- launch ----------
extern "C" void kernel_launch(void* const* d_in, const int* in_sizes, int n_in,
                              void* d_out, int out_size, void* d_ws, size_t ws_size,
                              hipStream_t stream) {
    const float* x  = (const float*)d_in[0];
    const float* KE = (const float*)d_in[1];
    const float* cw = (const float*)d_in[2];
    const float* cb = (const float*)d_in[3];
    const float* dw = (const float*)d_in[4];
    const float* db = (const float*)d_in[5];
    float* out = (float*)d_out;

    char* ws = (char*)d_ws;
    float* xsum           = (float*)(ws + 0);            // 16*256*4    = 16 KB
    float* mix            = (float*)(ws + 16384);        // 16*8*4      = 512 B
    unsigned short* Wg    = (unsigned short*)(ws + 32768);            // 18.87 MB
    unsigned short* Xp    = (unsigned short*)(ws + 32768 + 18874368); // 35.68 MB

    hipMemsetAsync(xsum, 0, B_ * C_ * sizeof(float), stream);
    k_xpose  <<<dim3(B_ * H_ * 4),    dim3(256), 0, stream>>>(x, Xp, xsum);
    k_mix    <<<dim3(B_),             dim3(256), 0, stream>>>(xsum, cw, cb, dw, db, mix);
    k_mixkern<<<dim3(C_ * 2),         dim3(256), 0, stream>>>(KE, mix, Wg);
    k_gemm   <<<dim3(256),            dim3(512), 0, stream>>>(Wg, Xp, out);
}